// Round 4
// baseline (43926.364 us; speedup 1.0000x reference)
//
#include <hip/hip_runtime.h>
#include <hip/hip_cooperative_groups.h>
#include <cstdint>
#include <cmath>

namespace cg = cooperative_groups;

#define DEVI __device__ __forceinline__

constexpr int B_ = 16, TENC_ = 168, TBERT_ = 96, TOUT_ = 200;
constexpr int NMEL_ = 80, ENC_ = 512, ARNN_ = 1024, PRE_ = 256, ATT_ = 128, NF_ = 32, KCV_ = 31;

// ---------------- workspace layout (float offsets) ----------------
constexpr size_t o_qWTa = 0;                               // [1024][128] transposed attn_q
constexpr size_t o_qWTb = o_qWTa + 1024*128;
constexpr size_t o_pall  = o_qWTb + 1024*128;              // [T][B][PRE]
constexpr size_t o_pball = o_pall + (size_t)TOUT_*B_*PRE_;
constexpr size_t o_pmem  = o_pball + (size_t)TOUT_*B_*PRE_; // [B][TENC][ATT]
constexpr size_t o_pbert = o_pmem + (size_t)B_*TENC_*ATT_;  // [B][TBERT][ATT]
constexpr size_t o_state = o_pbert + (size_t)B_*TBERT_*ATT_;
constexpr size_t o_ah   = o_state;                  // [2][B][ARNN] double-buffered (h: [b][u])
constexpr size_t o_ahb  = o_ah  + 2*B_*ARNN_;
constexpr size_t o_ac   = o_ahb + 2*B_*ARNN_;       // c: [u][b] layout
constexpr size_t o_acb  = o_ac  + B_*ARNN_;
constexpr size_t o_dh   = o_acb + B_*ARNN_;         // [b][u]
constexpr size_t o_dc   = o_dh  + B_*ARNN_;         // [u][b]
constexpr size_t o_dhb  = o_dc  + B_*ARNN_;         // [b][u]
constexpr size_t o_dcb  = o_dhb + B_*ARNN_;         // [u][b]
constexpr size_t o_ctx  = o_dcb + B_*ARNN_;         // [B][ENC]
constexpr size_t o_ctxb = o_ctx + B_*ENC_;
constexpr size_t o_aw   = o_ctxb+ B_*ENC_;          // [B][TENC]
constexpr size_t o_awc  = o_aw  + B_*TENC_;
constexpr size_t o_awb  = o_awc + B_*TENC_;         // [B][TBERT]
constexpr size_t o_awcb = o_awb + B_*TBERT_;
constexpr size_t o_zend = o_awcb+ B_*TBERT_;
constexpr size_t ZCOUNT = o_zend - o_state;
constexpr size_t o_gd   = o_zend;                   // drnn gates [4096][B]
constexpr size_t o_gdb  = o_gd + 4096*B_;
constexpr size_t o_dhall   = o_gdb + 4096*B_;       // [T][B][DRNN]
constexpr size_t o_ctxall  = o_dhall + (size_t)TOUT_*B_*ARNN_;
constexpr size_t o_ctxball = o_ctxall + (size_t)TOUT_*B_*ENC_;

// output offsets (floats)
constexpr size_t OO_MEL  = 0;
constexpr size_t OO_GATE = (size_t)B_*NMEL_*TOUT_;
constexpr size_t OO_AL   = OO_GATE + (size_t)B_*TOUT_;
constexpr size_t OO_ALB  = OO_AL + (size_t)B_*TOUT_*TENC_;

DEVI float sigf(float x) { return 1.f / (1.f + expf(-x)); }

DEVI float dotseg(const float* __restrict__ w, const float* __restrict__ x, int n) {
  const float4* wp = reinterpret_cast<const float4*>(w);
  const float4* xp = reinterpret_cast<const float4*>(x);
  float a0 = 0, a1 = 0, a2 = 0, a3 = 0;
  int n4 = n >> 2;
#pragma unroll 4
  for (int i = 0; i < n4; ++i) {
    float4 wv = wp[i], xv = xp[i];
    a0 = fmaf(wv.x, xv.x, a0); a1 = fmaf(wv.y, xv.y, a1);
    a2 = fmaf(wv.z, xv.z, a2); a3 = fmaf(wv.w, xv.w, a3);
  }
  return (a0 + a1) + (a2 + a3);
}

// async global->LDS, 16B per lane, wave-uniform LDS base
DEVI void gl_lds16(const float* g, float* l) {
  auto gp = (const __attribute__((address_space(1))) float*)g;
  auto lp = (__attribute__((address_space(3))) float*)l;
  __builtin_amdgcn_global_load_lds(gp, lp, 16, 0, 0);
}

// ================= prolog: prenet(all t), pmem, pbert, q-transposes, zero states =================
__global__ __launch_bounds__(256) void k_prolog(
    const float* __restrict__ dec, const float* __restrict__ pw1, const float* __restrict__ pw2,
    const float* __restrict__ pbw1, const float* __restrict__ pbw2,
    const float* __restrict__ memory, const float* __restrict__ embeddings,
    const float* __restrict__ am, const float* __restrict__ abm,
    const float* __restrict__ aq, const float* __restrict__ abq,
    float* __restrict__ ws)
{
  __shared__ float smem[10240];
  int bid = blockIdx.x, tid = threadIdx.x;
  if (bid < 200) {
    int t = bid;
    float* xl  = smem;                // [16][80]
    float* h1  = smem + 1280;         // [16][256]
    float* h1b = smem + 1280 + 4096;  // [16][256]
    for (int i = tid; i < 16*80; i += 256) {
      int b = i / 80, m = i % 80;
      xl[i] = (t == 0) ? 0.f : dec[((size_t)b*80 + m)*200 + (t-1)];
    }
    __syncthreads();
    int j = tid;
    for (int b = 0; b < 16; ++b) {
      const float* x = xl + b*80;
      float a1 = 0, a2 = 0;
#pragma unroll 4
      for (int m = 0; m < 80; ++m) { a1 = fmaf(pw1[j*80+m], x[m], a1); a2 = fmaf(pbw1[j*80+m], x[m], a2); }
      h1[b*256+j]  = fmaxf(a1, 0.f);
      h1b[b*256+j] = fmaxf(a2, 0.f);
    }
    __syncthreads();
    for (int b = 0; b < 16; ++b) {
      float a1 = 0, a2 = 0;
#pragma unroll 4
      for (int k = 0; k < 256; ++k) { a1 = fmaf(pw2[j*256+k], h1[b*256+k], a1); a2 = fmaf(pbw2[j*256+k], h1b[b*256+k], a2); }
      ws[o_pall  + ((size_t)t*16+b)*256 + j] = fmaxf(a1, 0.f);
      ws[o_pball + ((size_t)t*16+b)*256 + j] = fmaxf(a2, 0.f);
    }
  } else if (bid < 368) {
    int r0 = (bid - 200) * 16;
    float* ml = smem;  // [16][512]
    for (int i = tid; i < 16*512; i += 256) ml[i] = memory[(size_t)r0*512 + i];
    __syncthreads();
    int a = tid & 127, ro = tid >> 7;
    for (int row = ro; row < 16; row += 2) {
      const float* x = ml + row*512; const float* w = am + (size_t)a*512;
      float acc = 0;
#pragma unroll 4
      for (int e = 0; e < 512; ++e) acc = fmaf(w[e], x[e], acc);
      ws[o_pmem + (size_t)(r0+row)*128 + a] = acc;
    }
  } else if (bid < 464) {
    int r0 = (bid - 368) * 16;
    float* ml = smem;
    for (int i = tid; i < 16*512; i += 256) ml[i] = embeddings[(size_t)r0*512 + i];
    __syncthreads();
    int a = tid & 127, ro = tid >> 7;
    for (int row = ro; row < 16; row += 2) {
      const float* x = ml + row*512; const float* w = abm + (size_t)a*512;
      float acc = 0;
#pragma unroll 4
      for (int e = 0; e < 512; ++e) acc = fmaf(w[e], x[e], acc);
      ws[o_pbert + (size_t)(r0+row)*128 + a] = acc;
    }
  } else if (bid < 466) {
    const float* src = (bid == 464) ? aq : abq;
    float* dst = ws + ((bid == 464) ? o_qWTa : o_qWTb);
    for (int i = tid; i < 1024*128; i += 256) {
      int k = i >> 7, a = i & 127;
      dst[i] = src[(size_t)a*1024 + k];
    }
  } else {
    int zi = bid - 466;  // 8 zero blocks
    for (size_t i = (size_t)zi*256 + tid; i < ZCOUNT; i += 8*256) ws[o_state + i] = 0.f;
  }
}

// x-piece source for a 256-float K-segment (k0 multiple of 256; piece boundaries all multiples of 256)
DEVI const float* seg_src(int type, int k0, int b, int t, const float* __restrict__ ws) {
  if (type <= 1) {
    if (k0 < 256)  return ws + (type ? o_pball : o_pall) + ((size_t)t*16 + b)*256 + k0;
    if (k0 < 768)  return ws + (type ? o_ctxb : o_ctx) + (size_t)b*512 + (k0 - 256);
    return ws + (type ? o_ahb : o_ah) + (size_t)((t+1)&1)*(B_*ARNN_) + (size_t)b*1024 + (k0 - 768);
  } else if (type == 2) {
    int tp = (t-1) & 1;
    if (k0 < 1024) return ws + o_ah  + (size_t)tp*(B_*ARNN_) + (size_t)b*1024 + k0;
    if (k0 < 2048) return ws + o_ahb + (size_t)tp*(B_*ARNN_) + (size_t)b*1024 + (k0-1024);
    if (k0 < 2560) return ws + o_ctx  + (size_t)b*512 + (k0-2048);
    if (k0 < 3072) return ws + o_ctxb + (size_t)b*512 + (k0-2560);
    return ws + o_dh + (size_t)b*1024 + (k0-3072);
  } else {
    int tp = (t-1) & 1;
    if (k0 < 1024) return ws + o_ahb + (size_t)tp*(B_*ARNN_) + (size_t)b*1024 + k0;
    if (k0 < 1536) return ws + o_ctxb + (size_t)b*512 + (k0-1024);
    return ws + o_dhb + (size_t)b*1024 + (k0-1536);
  }
}

DEVI void fillr(int type, int r, float* __restrict__ dst, int wl, int lane, int t,
                const float* __restrict__ ws) {
  int k0 = r * 256;
#pragma unroll
  for (int o = 0; o < 4; ++o) {
    int b = o*4 + wl;
    const float* s = seg_src(type, k0, b, t, ws) + 4*lane;
    gl_lds16(s, dst + b*256);
  }
}

DEVI void loadw(float4 w[8], const float* __restrict__ Wih, const float* __restrict__ Whh,
                int IH, int row0, int r, int lane) {
  int k0 = r * 256;
  const float* base; size_t st;
  if (k0 < IH) { base = Wih + (size_t)row0*IH + k0; st = IH; }
  else         { base = Whh + (size_t)row0*1024 + (k0 - IH); st = 1024; }
  base += 4*lane;
#pragma unroll
  for (int i = 0; i < 8; ++i) w[i] = *(const float4*)(base + st*i);
}

DEVI void computeg(const float* __restrict__ buf, const float4 w[8], int lane, float acc[8][16]) {
  const float4* xb = (const float4*)buf;
#pragma unroll
  for (int b = 0; b < 16; ++b) {
    float4 xv = xb[b*64 + lane];
#pragma unroll
    for (int rr = 0; rr < 8; ++rr) {
      acc[rr][b] = fmaf(w[rr].x, xv.x, acc[rr][b]);
      acc[rr][b] = fmaf(w[rr].y, xv.y, acc[rr][b]);
      acc[rr][b] = fmaf(w[rr].z, xv.z, acc[rr][b]);
      acc[rr][b] = fmaf(w[rr].w, xv.w, acc[rr][b]);
    }
  }
}

// within-wave reduce over 64 k-lanes: res[ph] = full sums; LDS scratch 32x68 per wave
DEVI void wave_reduce(float acc[8][16], float* __restrict__ red, int lane, float res[4]) {
  int o = lane & 31, half = lane >> 5;
#pragma unroll
  for (int ph = 0; ph < 4; ++ph) {
#pragma unroll
    for (int j = 0; j < 32; ++j)
      red[j*68 + lane] = acc[2*ph + (j >> 4)][j & 15];
    float s = 0;
    const float* rrow = red + o*68 + half*32;
#pragma unroll
    for (int j = 0; j < 8; ++j) {
      float4 v = *(const float4*)(rrow + 4*j);
      s += (v.x + v.y) + (v.z + v.w);
    }
    res[ph] = s + __shfl_xor(s, 32);
  }
}

// ================= persistent kernel: full 201-step decoder loop =================
__global__ __launch_bounds__(512, 2) void k_persist(
    const float* __restrict__ memory, const float* __restrict__ embeddings,
    const float* __restrict__ a_wih, const float* __restrict__ a_whh, const float* __restrict__ a_b,
    const float* __restrict__ ab_wih, const float* __restrict__ ab_whh, const float* __restrict__ ab_b,
    const float* __restrict__ d_wih, const float* __restrict__ d_whh, const float* __restrict__ d_b,
    const float* __restrict__ db_wih, const float* __restrict__ db_whh, const float* __restrict__ db_b,
    const float* __restrict__ a_conv, const float* __restrict__ a_loc, const float* __restrict__ a_v,
    const float* __restrict__ ab_conv, const float* __restrict__ ab_loc, const float* __restrict__ ab_v,
    float* __restrict__ ws, float* __restrict__ out)
{
  __shared__ __align__(16) float dlds[16384];   // 64KB: 2 halves x 2 bufs x [16][256]
  cg::grid_group grid = cg::this_grid();
  int bid = blockIdx.x, tid = threadIdx.x;
  int wv = tid >> 6, lane = tid & 63;
  int half = wv >> 2, wl = wv & 3;              // wl = gate for GEMM role
  int grp = bid >> 7, oct = bid & 127, u0 = oct * 8;
  int type = (half == 0) ? grp : 2 + grp;

  int R, IH; const float *Wih, *Whh;
  switch (type) {
    case 0:  R = 7;  IH = 768;  Wih = a_wih;  Whh = a_whh;  break;
    case 1:  R = 7;  IH = 768;  Wih = ab_wih; Whh = ab_whh; break;
    case 2:  R = 16; IH = 3072; Wih = d_wih;  Whh = d_whh;  break;
    default: R = 10; IH = 1536; Wih = db_wih; Whh = db_whh; break;
  }
  int row0 = wl*1024 + u0;
  float* mybuf = dlds + half*8192;

  for (int t = 0; t <= TOUT_; ++t) {
    // ---------------- phase A: 4 LSTM gate GEMMs ----------------
    bool act = (type <= 1) ? (t < TOUT_) : (t >= 1);
    int R0 = (t < TOUT_) ? 7 : 0;
    int R1 = (t >= 1) ? (grp ? 10 : 16) : 0;
    int maxr = (R0 > R1) ? R0 : R1;

    float acc[8][16];
#pragma unroll
    for (int rr = 0; rr < 8; ++rr)
#pragma unroll
      for (int b = 0; b < 16; ++b) acc[rr][b] = 0.f;

    float4 wc[8];
    if (act) { fillr(type, 0, mybuf, wl, lane, t, ws); loadw(wc, Wih, Whh, IH, row0, 0, lane); }
    __syncthreads();
    int p = 0;
    for (int r = 0; r < maxr; ++r) {
      float4 wn[8];
      bool a0 = act && (r < R);
      bool a1 = act && (r + 1 < R);
      if (a1) { fillr(type, r+1, mybuf + (p^1)*4096, wl, lane, t, ws);
                loadw(wn, Wih, Whh, IH, row0, r+1, lane); }
      if (a0) computeg(mybuf + p*4096, wc, lane, acc);
      __syncthreads();
      p ^= 1;
#pragma unroll
      for (int i = 0; i < 8; ++i) wc[i] = wn[i];
    }

    float res[4];
    if (half == 0 && act) wave_reduce(acc, dlds + wl*2176, lane, res);
    __syncthreads();
    if (half == 1 && act) wave_reduce(acc, dlds + wl*2176, lane, res);
    if (half == 1 && act && lane < 32) {
      float* gout = ws + (grp ? o_gdb : o_gd);
      int o = lane;
#pragma unroll
      for (int ph = 0; ph < 4; ++ph)
        gout[(size_t)(wl*1024 + u0 + 2*ph + (o >> 4))*16 + (o & 15)] = res[ph];
    }
    __syncthreads();
    if (half == 0 && act && lane < 32) {   // gbuf overlay at dlds[0..512)
      const float* bias = grp ? ab_b : a_b;
      int o = lane;
#pragma unroll
      for (int ph = 0; ph < 4; ++ph) {
        int j = 2*ph + (o >> 4), b = o & 15;
        dlds[wl*128 + j*16 + b] = res[ph] + bias[wl*1024 + u0 + j];
      }
    }
    __syncthreads();
    if (tid < 128 && t < TOUT_) {          // arnn pointwise
      int j = tid >> 4, b = tid & 15, u = u0 + j;
      float gi = dlds[0*128 + j*16+b], gf = dlds[1*128 + j*16+b];
      float gg = dlds[2*128 + j*16+b], go = dlds[3*128 + j*16+b];
      float* cst  = ws + (grp ? o_acb : o_ac);
      float* hcur = ws + (grp ? o_ahb : o_ah) + (size_t)(t&1)*(B_*ARNN_);
      float co = cst[u*16 + b];
      float cn = sigf(gf)*co + sigf(gi)*tanhf(gg);
      float hn = sigf(go)*tanhf(cn);
      cst[u*16 + b] = cn;
      hcur[b*1024 + u] = hn;
    }
    grid.sync();

    // ---------------- phase B: attention x2 + drnn pointwise ----------------
    if (bid < 32) {
      if (t < TOUT_) {
        bool isB = bid >= 16; int b = bid & 15;
        int T = isB ? TBERT_ : TENC_;
        const float* mem   = isB ? embeddings : memory;
        const float* pmemB = ws + (isB ? o_pbert : o_pmem);
        const float* qWT   = ws + (isB ? o_qWTb : o_qWTa);
        const float* convW = isB ? ab_conv : a_conv;
        const float* locW  = isB ? ab_loc : a_loc;
        const float* vW    = isB ? ab_v : a_v;
        const float* hq = ws + (isB ? o_ahb : o_ah) + (size_t)(t&1)*(B_*ARNN_) + (size_t)b*ARNN_;
        float* awS  = ws + (isB ? o_awb : o_aw) + (size_t)b*T;
        float* awcS = ws + (isB ? o_awcb : o_awc) + (size_t)b*T;
        float* ctxS = ws + (isB ? o_ctxb : o_ctx) + (size_t)b*ENC_;
        float* ctxAll = ws + (isB ? o_ctxball : o_ctxall) + ((size_t)t*16 + b)*ENC_;
        float* alOut = out + (isB ? OO_ALB : OO_AL) + ((size_t)b*TOUT_ + t)*T;

        float* ah_l = dlds;            // 1024
        float* pqp  = dlds + 1024;     // 512
        float* pq_s = dlds + 1536;     // 128
        float* awp0 = dlds + 1664;     // 208
        float* awp1 = dlds + 1872;     // 208
        float* cw_s = dlds + 2080;     // 1984
        float* vv   = dlds + 4064;     // 128
        float* fmT  = dlds + 4192;     // 5376
        float* ep_s = dlds + 9568;     // 336
        float* wl_s = dlds + 9904;     // 168
        float* smx  = dlds + 10072;    // 2

        for (int i = tid; i < 1024; i += 512) ah_l[i] = hq[i];
        for (int i = tid; i < NF_*2*KCV_; i += 512) cw_s[i] = convW[i];
        for (int i = tid; i < 128; i += 512) vv[i] = vW[i];
        for (int i = tid; i < T + 30; i += 512) {
          bool in = (i >= 15) && (i < T + 15);
          awp0[i] = in ? awS[i-15] : 0.f;
          awp1[i] = in ? awcS[i-15] : 0.f;
        }
        __syncthreads();
        {
          int a = tid & 127, hf = tid >> 7;
          float acc2 = 0;
          for (int k = hf*256; k < hf*256 + 256; ++k) acc2 = fmaf(qWT[(size_t)k*128 + a], ah_l[k], acc2);
          pqp[hf*128 + a] = acc2;
        }
        __syncthreads();
        if (tid < 128) pq_s[tid] = pqp[tid] + pqp[128+tid] + pqp[256+tid] + pqp[384+tid];
        __syncthreads();
        for (int idx = tid; idx < T*NF_; idx += 512) {
          int tt = idx >> 5, f = idx & 31;
          const float* c0 = cw_s + f*62;
          float s = 0;
#pragma unroll
          for (int kk = 0; kk < 31; ++kk)
            s = fmaf(awp0[tt+kk], c0[kk], fmaf(awp1[tt+kk], c0[31+kk], s));
          fmT[tt*32 + f] = s;
        }
        __syncthreads();
        {
          int a = tid & 127;
          float la[32];
#pragma unroll
          for (int f = 0; f < 32; ++f) la[f] = locW[a*32 + f];
          float pqr = pq_s[a], vr = vv[a];
          for (int idx = tid; idx < T*128; idx += 512) {
            int tt = idx >> 7;
            float pl = 0;
#pragma unroll
            for (int f = 0; f < 32; ++f) pl = fmaf(fmT[tt*32 + f], la[f], pl);
            float s = vr * tanhf(pqr + pl + pmemB[((size_t)b*T + tt)*128 + a]);
#pragma unroll
            for (int off = 1; off < 64; off <<= 1) s += __shfl_xor(s, off);
            if ((tid & 63) == 0) ep_s[tt*2 + ((idx >> 6) & 1)] = s;
          }
        }
        __syncthreads();
        if (tid < 64) {
          float m = -1e30f;
          for (int i = tid; i < T; i += 64) m = fmaxf(m, ep_s[2*i] + ep_s[2*i+1]);
#pragma unroll
          for (int off = 1; off < 64; off <<= 1) m = fmaxf(m, __shfl_xor(m, off));
          float ssum = 0;
          for (int i = tid; i < T; i += 64) ssum += expf(ep_s[2*i] + ep_s[2*i+1] - m);
#pragma unroll
          for (int off = 1; off < 64; off <<= 1) ssum += __shfl_xor(ssum, off);
          if (tid == 0) { smx[0] = m; smx[1] = 1.f / ssum; }
        }
        __syncthreads();
        for (int i = tid; i < T; i += 512) {
          float wv2 = expf(ep_s[2*i] + ep_s[2*i+1] - smx[0]) * smx[1];
          wl_s[i] = wv2;
          awS[i] = wv2;
          awcS[i] += wv2;
          alOut[i] = wv2;
        }
        __syncthreads();
        {  // ctx = w @ mem, 4-way ILP
          float a0 = 0, a1 = 0, a2 = 0, a3 = 0;
          const float* mb = mem + (size_t)b*T*512 + tid;
          int tt = 0;
          for (; tt + 4 <= T; tt += 4) {
            a0 = fmaf(wl_s[tt],   mb[(size_t)tt*512],     a0);
            a1 = fmaf(wl_s[tt+1], mb[(size_t)(tt+1)*512], a1);
            a2 = fmaf(wl_s[tt+2], mb[(size_t)(tt+2)*512], a2);
            a3 = fmaf(wl_s[tt+3], mb[(size_t)(tt+3)*512], a3);
          }
          for (; tt < T; ++tt) a0 = fmaf(wl_s[tt], mb[(size_t)tt*512], a0);
          float acc2 = (a0 + a1) + (a2 + a3);
          ctxS[tid] = acc2;
          ctxAll[tid] = acc2;
        }
      }
    } else {
      if (t >= 1) {  // drnn/drnnb (t-1) pointwise
        int gid = (bid - 32)*512 + tid;
        if (gid < 32768) {
          int L = gid >> 14;
          int rem = gid & 16383;
          int u = rem >> 4, b = rem & 15;
          const float* g = ws + (L ? o_gdb : o_gd);
          const float* bias = L ? db_b : d_b;
          float* h  = ws + (L ? o_dhb : o_dh);
          float* cc = ws + (L ? o_dcb : o_dc);
          float gi = g[(size_t)u*16 + b]        + bias[u];
          float gf = g[(size_t)(1024+u)*16 + b] + bias[1024+u];
          float gg = g[(size_t)(2048+u)*16 + b] + bias[2048+u];
          float go = g[(size_t)(3072+u)*16 + b] + bias[3072+u];
          float co = cc[u*16 + b];
          float cn = sigf(gf)*co + sigf(gi)*tanhf(gg);
          float hn = sigf(go)*tanhf(cn);
          cc[u*16 + b] = cn;
          h[b*1024 + u] = hn;
          if (L == 0) ws[o_dhall + ((size_t)(t-1)*16 + b)*1024 + u] = hn;
        }
      }
    }
    grid.sync();
  }
}

// ================= epilog: batched projection + gate =================
__global__ __launch_bounds__(512) void k_proj(
    const float* __restrict__ pw, const float* __restrict__ pb,
    const float* __restrict__ gw, const float* __restrict__ gb,
    const float* __restrict__ ws, float* __restrict__ out)
{
  int t = blockIdx.x, tid = threadIdx.x;
  for (int o = tid; o < 16*81; o += 512) {
    int b = o / 81, j = o % 81;
    const float* wrow = (j < 80) ? (pw + (size_t)j*2048) : gw;
    const float* xd  = ws + o_dhall   + ((size_t)t*16 + b)*1024;
    const float* xc  = ws + o_ctxall  + ((size_t)t*16 + b)*512;
    const float* xcb = ws + o_ctxball + ((size_t)t*16 + b)*512;
    float acc = dotseg(wrow, xd, 1024) + dotseg(wrow + 1024, xc, 512)
              + dotseg(wrow + 1536, xcb, 512) + ((j < 80) ? pb[j] : gb[0]);
    if (j < 80) out[OO_MEL + ((size_t)b*80 + j)*200 + t] = acc;
    else        out[OO_GATE + (size_t)b*200 + t] = acc;
  }
}

extern "C" void kernel_launch(void* const* d_in, const int* in_sizes, int n_in,
                              void* d_out, int out_size, void* d_ws, size_t ws_size,
                              hipStream_t stream) {
  (void)in_sizes; (void)n_in; (void)out_size; (void)ws_size;
  const float* memory     = (const float*)d_in[0];
  const float* embeddings = (const float*)d_in[1];
  const float* dec      = (const float*)d_in[2];
  const float* pw1      = (const float*)d_in[3];
  const float* pw2      = (const float*)d_in[4];
  const float* pbw1     = (const float*)d_in[5];
  const float* pbw2     = (const float*)d_in[6];
  const float* a_wih    = (const float*)d_in[7];
  const float* a_whh    = (const float*)d_in[8];
  const float* a_b      = (const float*)d_in[9];
  const float* ab_wih   = (const float*)d_in[10];
  const float* ab_whh   = (const float*)d_in[11];
  const float* ab_b     = (const float*)d_in[12];
  const float* a_q      = (const float*)d_in[13];
  const float* a_m      = (const float*)d_in[14];
  const float* a_conv   = (const float*)d_in[15];
  const float* a_loc    = (const float*)d_in[16];
  const float* a_v      = (const float*)d_in[17];
  const float* ab_q     = (const float*)d_in[18];
  const float* ab_m     = (const float*)d_in[19];
  const float* ab_conv  = (const float*)d_in[20];
  const float* ab_loc   = (const float*)d_in[21];
  const float* ab_v     = (const float*)d_in[22];
  const float* d_wih    = (const float*)d_in[23];
  const float* d_whh    = (const float*)d_in[24];
  const float* d_b      = (const float*)d_in[25];
  const float* db_wih   = (const float*)d_in[26];
  const float* db_whh   = (const float*)d_in[27];
  const float* db_b     = (const float*)d_in[28];
  const float* proj_w   = (const float*)d_in[29];
  const float* proj_b   = (const float*)d_in[30];
  const float* gate_w   = (const float*)d_in[31];
  const float* gate_b   = (const float*)d_in[32];
  float* ws  = (float*)d_ws;
  float* out = (float*)d_out;

  k_prolog<<<dim3(474), dim3(256), 0, stream>>>(dec, pw1, pw2, pbw1, pbw2,
      memory, embeddings, a_m, ab_m, a_q, ab_q, ws);

  void* args[] = {
    (void*)&memory, (void*)&embeddings,
    (void*)&a_wih, (void*)&a_whh, (void*)&a_b,
    (void*)&ab_wih, (void*)&ab_whh, (void*)&ab_b,
    (void*)&d_wih, (void*)&d_whh, (void*)&d_b,
    (void*)&db_wih, (void*)&db_whh, (void*)&db_b,
    (void*)&a_conv, (void*)&a_loc, (void*)&a_v,
    (void*)&ab_conv, (void*)&ab_loc, (void*)&ab_v,
    (void*)&ws, (void*)&out
  };
  hipLaunchCooperativeKernel(reinterpret_cast<void*>(&k_persist),
                             dim3(256), dim3(512), args, 0, stream);

  k_proj<<<dim3(200), dim3(512), 0, stream>>>(proj_w, proj_b, gate_w, gate_b, ws, out);
}